// Round 5
// baseline (1978.355 us; speedup 1.0000x reference)
//
#include <hip/hip_runtime.h>
#include <hip/hip_fp16.h>
#include <math.h>

// Feature dim 64 is processed as 4 slices of 16 features. Each slice's gather
// buffer is (N+1) rows x 16 fp16 = 3.2 MB -> fits one XCD's 4 MB L2. Row N is
// a zeroed dummy row used to mask tail edges (branch-free inner loop).

// ---------------- init / histogram / norm ----------------

__global__ void zero_i32(int* __restrict__ p, int n) {
    int i = blockIdx.x * blockDim.x + threadIdx.x;
    if (i < n) p[i] = 0;
}

__global__ void hist_k(const int* __restrict__ dst, int E, int* __restrict__ counts) {
    int e = blockIdx.x * blockDim.x + threadIdx.x;
    if (e < E) atomicAdd(&counts[dst[e]], 1);
}

__global__ void dinv_k(const int* __restrict__ counts, float* __restrict__ dinv, int N) {
    int i = blockIdx.x * blockDim.x + threadIdx.x;
    if (i < N) dinv[i] = rsqrtf((float)(counts[i] + 1));  // +1 self-loop
}

// zero the dummy row (index N) of the three sliced fp16 buffers
__global__ void zero_dummy(__half2* __restrict__ b0, __half2* __restrict__ b1,
                           __half2* __restrict__ b2, int N) {
    int t = threadIdx.x;           // 96 = 3 buffers * 4 slices * 8 half2
    if (t >= 96) return;
    __half2* b = (t < 32) ? b0 : (t < 64) ? b1 : b2;
    int r = t & 31, s = r >> 3, h = r & 7;
    b[((size_t)s * (N + 1) + N) * 8 + h] = __floats2half2_rn(0.f, 0.f);
}

// ---------------- 3-pass exclusive scan (1024 elems / block) ----------------

__global__ void scan_pass1(const int* __restrict__ counts, int N, int* __restrict__ bsum) {
    __shared__ int s[256];
    int t = threadIdx.x;
    int base = blockIdx.x * 1024 + t * 4;
    int sum = 0;
    for (int j = 0; j < 4; ++j) { int i = base + j; if (i < N) sum += counts[i]; }
    s[t] = sum; __syncthreads();
    for (int off = 128; off > 0; off >>= 1) {
        if (t < off) s[t] += s[t + off];
        __syncthreads();
    }
    if (t == 0) bsum[blockIdx.x] = s[0];
}

__global__ void scan_pass2(const int* __restrict__ bsum, int nb, int* __restrict__ boff) {
    if (blockIdx.x == 0 && threadIdx.x == 0) {
        int r = 0;
        for (int b = 0; b < nb; ++b) { boff[b] = r; r += bsum[b]; }
    }
}

__global__ void scan_pass3(const int* __restrict__ counts, int N,
                           const int* __restrict__ boff, int* __restrict__ rowptr, int E) {
    __shared__ int s[256];
    int t = threadIdx.x;
    int base = blockIdx.x * 1024 + t * 4;
    int c[4]; int sum = 0;
    for (int j = 0; j < 4; ++j) { int i = base + j; c[j] = (i < N) ? counts[i] : 0; sum += c[j]; }
    s[t] = sum; __syncthreads();
    for (int off = 1; off < 256; off <<= 1) {
        int v = (t >= off) ? s[t - off] : 0;
        __syncthreads();
        s[t] += v;
        __syncthreads();
    }
    int excl = s[t] - sum + boff[blockIdx.x];
    for (int j = 0; j < 4; ++j) {
        int i = base + j;
        if (i < N) { rowptr[i] = excl; excl += c[j]; }
    }
    if (blockIdx.x == 0 && t == 0) rowptr[N] = E;
}

// ---------------- CSR fill: col index only (4B scatter, nontemporal) ----------------

__global__ void fill_k(const int* __restrict__ src, const int* __restrict__ dst, int E,
                       const int* __restrict__ rowptr,
                       int* __restrict__ cursor, int* __restrict__ col) {
    int e = blockIdx.x * blockDim.x + threadIdx.x;
    if (e >= E) return;
    int s = src[e], d = dst[e];
    int pos = rowptr[d] + atomicAdd(&cursor[d], 1);
    __builtin_nontemporal_store(s, &col[pos]);
}

// ---------------- g0 = x @ W : LDS-tiled, 128 rows x 64 cols per block ----------------
// Emits fp32 g0 (teleport term) and the PRESCALED, SLICED fp16 gather buffer
// gh0[s][(n)*8 + h] = dinv[n] * g0[n, 16s + 2h .. 16s + 2h + 1].

__global__ void __launch_bounds__(256) gemm_k(const float* __restrict__ x,
                                              const float* __restrict__ W,
                                              const float* __restrict__ dinv,
                                              float* __restrict__ g0,
                                              __half2* __restrict__ gh0, int N) {
    __shared__ float Ws[128 * 64];    // 32 KB, row-major [k][j]
    __shared__ float xs[128 * 133];   // 68 KB, stride 133 -> conflict-free compute reads
    int t = threadIdx.x;
    for (int i = t; i < 128 * 64; i += 256) Ws[i] = W[i];
    int n0 = blockIdx.x * 128;
    for (int f = t; f < 128 * 32; f += 256) {  // f indexes a float4: r = f>>5, c4 = f&31
        int r = f >> 5, c4 = f & 31;
        int n = n0 + r;
        float4 v = (n < N) ? ((const float4*)x)[(size_t)n * 32 + c4]
                           : make_float4(0.f, 0.f, 0.f, 0.f);
        float* dp = &xs[r * 133 + c4 * 4];
        dp[0] = v.x; dp[1] = v.y; dp[2] = v.z; dp[3] = v.w;
    }
    __syncthreads();
    int tr = t & 15, tc = t >> 4;      // j0 = 4*tr (cols), r0 = 8*tc (rows)
    int j0 = tr * 4, r0 = tc * 8;
    float acc[8][4] = {};
#pragma unroll 4
    for (int k = 0; k < 128; ++k) {
        float4 wv = *(const float4*)&Ws[k * 64 + j0];
#pragma unroll
        for (int i = 0; i < 8; ++i) {
            float xv = xs[(r0 + i) * 133 + k];
            acc[i][0] += xv * wv.x; acc[i][1] += xv * wv.y;
            acc[i][2] += xv * wv.z; acc[i][3] += xv * wv.w;
        }
    }
    int sl = j0 >> 4, h0 = (j0 & 15) >> 1;
#pragma unroll
    for (int i = 0; i < 8; ++i) {
        int n = n0 + r0 + i;
        if (n < N) {
            float4 v = make_float4(acc[i][0], acc[i][1], acc[i][2], acc[i][3]);
            *(float4*)&g0[(size_t)n * 64 + j0] = v;
            float dn = dinv[n];
            __half2* gp = &gh0[((size_t)sl * (N + 1) + n) * 8 + h0];
            gp[0] = __floats2half2_rn(v.x * dn, v.y * dn);
            gp[1] = __floats2half2_rn(v.z * dn, v.w * dn);
        }
    }
}

// ---------------- propagation (per-slice) ----------------
// Buffers hold g_hat = dinv[n]*h[n] (fp16, 4 slices of 16 features).
//   S = sum_e g_hat[src_e];  r = 0.9*dinv[d]*(S + g_hat[d]) + 0.1*g0[d]
// One wave per (row, slice). A row-slice is 8 half2 -> 8 lanes, so one gather
// instruction covers EIGHT edges (lane groups). Cols for 64 edges come from
// one coalesced nontemporal load, distributed via ds_bpermute (__shfl).
// Tail edges redirect to zeroed dummy row N (branch-free).

__global__ void __launch_bounds__(256) prop_k(const __half2* __restrict__ gin,
                                              const float* __restrict__ g0,
                                              __half2* __restrict__ gout,
                                              float* __restrict__ outf,
                                              const int* __restrict__ rowptr,
                                              const int* __restrict__ cols,
                                              const float* __restrict__ dinv,
                                              const float* __restrict__ bias,
                                              int N, int final_step) {
    int slice = blockIdx.x & 3;
    int row = (blockIdx.x >> 2) * 4 + (threadIdx.x >> 6);
    if (row >= N) return;
    int lane = threadIdx.x & 63;
    int grp = lane >> 3, lf = lane & 7;
    const __half2* gs = gin + (size_t)slice * (N + 1) * 8;

    int beg = rowptr[row], end = rowptr[row + 1];
    int deg = end - beg;
    float ax = 0.f, ay = 0.f;

    for (int base = 0; base < deg; base += 64) {
        int m = deg - base; if (m > 64) m = 64;
        int idx = beg + base + (lane < m ? lane : 0);
        int ci = __builtin_nontemporal_load(&cols[idx]);
        for (int j = 0; j < m; j += 32) {         // 4 groups of 8 edges in flight
            int e0 = j + grp;
            int c0 = __shfl(ci, e0, 64);      if (e0 >= m)      c0 = N;
            int c1 = __shfl(ci, e0 + 8, 64);  if (e0 + 8 >= m)  c1 = N;
            int c2 = __shfl(ci, e0 + 16, 64); if (e0 + 16 >= m) c2 = N;
            int c3 = __shfl(ci, e0 + 24, 64); if (e0 + 24 >= m) c3 = N;
            float2 f0 = __half22float2(gs[(size_t)c0 * 8 + lf]);
            float2 f1 = __half22float2(gs[(size_t)c1 * 8 + lf]);
            float2 f2 = __half22float2(gs[(size_t)c2 * 8 + lf]);
            float2 f3 = __half22float2(gs[(size_t)c3 * 8 + lf]);
            ax += f0.x; ay += f0.y; ax += f1.x; ay += f1.y;
            ax += f2.x; ay += f2.y; ax += f3.x; ay += f3.y;
        }
    }

    // reduce the 8 edge-groups (butterfly over lane bits 3..5)
    ax += __shfl(ax, lane ^ 8, 64);  ay += __shfl(ay, lane ^ 8, 64);
    ax += __shfl(ax, lane ^ 16, 64); ay += __shfl(ay, lane ^ 16, 64);
    ax += __shfl(ax, lane ^ 32, 64); ay += __shfl(ay, lane ^ 32, 64);

    if (grp == 0) {
        float di = dinv[row];
        float2 gi = __half22float2(gs[(size_t)row * 8 + lf]);   // self-loop term
        int fo = slice * 8 + lf;   // float2 offset within the 64-float row
        float2 g0v = ((const float2*)g0)[(size_t)row * 32 + fo];
        float rx = 0.9f * di * (ax + gi.x) + 0.1f * g0v.x;
        float ry = 0.9f * di * (ay + gi.y) + 0.1f * g0v.y;
        if (final_step) {
            float2 bv = ((const float2*)bias)[fo];
            ((float2*)outf)[(size_t)row * 32 + fo] = make_float2(rx + bv.x, ry + bv.y);
        } else {
            __half2* go = gout + (size_t)slice * (N + 1) * 8;
            go[(size_t)row * 8 + lf] = __floats2half2_rn(di * rx, di * ry);
        }
    }
}

// ---------------- launch ----------------

extern "C" void kernel_launch(void* const* d_in, const int* in_sizes, int n_in,
                              void* d_out, int out_size, void* d_ws, size_t ws_size,
                              hipStream_t stream) {
    const float* x  = (const float*)d_in[0];
    const int*   ei = (const int*)d_in[1];
    const float* W  = (const float*)d_in[2];
    const float* b  = (const float*)d_in[3];
    float* out = (float*)d_out;

    const int N = in_sizes[0] / 128;
    const int E = in_sizes[1] / 2;
    const int* src = ei;
    const int* dst = ei + E;

    // workspace carve-up (256 B aligned)
    char* w = (char*)d_ws;
    size_t off = 0;
    auto alloc = [&](size_t bytes) -> void* {
        void* p = w + off;
        off += (bytes + 255) & ~(size_t)255;
        return p;
    };
    const size_t slice_h2 = (size_t)(N + 1) * 8;           // half2 per slice
    float*   g0     = (float*)  alloc((size_t)N * 64 * 4);
    __half2* gh0    = (__half2*)alloc(slice_h2 * 4 * 4);   // 4 slices x 4B/half2
    __half2* bufA   = (__half2*)alloc(slice_h2 * 4 * 4);
    __half2* bufB   = (__half2*)alloc(slice_h2 * 4 * 4);
    int*     cols   = (int*)    alloc((size_t)E * 4);
    int*     rowptr = (int*)    alloc((size_t)(N + 1) * 4);
    int*     counts = (int*)    alloc((size_t)N * 4);
    float*   dinvv  = (float*)  alloc((size_t)N * 4);
    const int nb = (N + 1023) / 1024;
    int*     bsum   = (int*)    alloc((size_t)nb * 4);
    int*     boff   = (int*)    alloc((size_t)nb * 4);

    const int nblkN = (N + 255) / 256;
    const int nblkE = (E + 255) / 256;

    // build normalized adjacency (CSR by dst, col-only payload)
    zero_i32<<<nblkN, 256, 0, stream>>>(counts, N);
    hist_k<<<nblkE, 256, 0, stream>>>(dst, E, counts);
    dinv_k<<<nblkN, 256, 0, stream>>>(counts, dinvv, N);
    zero_dummy<<<1, 128, 0, stream>>>(gh0, bufA, bufB, N);
    scan_pass1<<<nb, 256, 0, stream>>>(counts, N, bsum);
    scan_pass2<<<1, 64, 0, stream>>>(bsum, nb, boff);
    scan_pass3<<<nb, 256, 0, stream>>>(counts, N, boff, rowptr, E);
    zero_i32<<<nblkN, 256, 0, stream>>>(counts, N);  // reuse as fill cursor
    fill_k<<<nblkE, 256, 0, stream>>>(src, dst, E, rowptr, counts, cols);

    // g0 = x @ W (propagation commutes with the linear head: (A h) W = A (h W))
    gemm_k<<<(N + 127) / 128, 256, 0, stream>>>(x, W, dinvv, g0, gh0, N);

    // K = 10 APPNP steps; grid = 4 slices x (N/4 rows-per-block)
    const int nrb = (N + 3) / 4;
    const int gridP = nrb * 4;
    const __half2* gin = gh0;
    __half2* pp[2] = {bufA, bufB};
    for (int k = 0; k < 10; ++k) {
        const bool fin = (k == 9);
        __half2* gout = pp[k & 1];
        prop_k<<<gridP, 256, 0, stream>>>(gin, g0, gout, out, rowptr, cols,
                                          dinvv, b, N, fin ? 1 : 0);
        gin = gout;
    }
}

// Round 6
// 1302.203 us; speedup vs baseline: 1.5192x; 1.5192x over previous
//
#include <hip/hip_runtime.h>
#include <hip/hip_fp16.h>
#include <math.h>

// ---------------- init / histogram / norm ----------------

__global__ void zero_i32(int* __restrict__ p, int n) {
    int i = blockIdx.x * blockDim.x + threadIdx.x;
    if (i < n) p[i] = 0;
}

__global__ void hist_k(const int* __restrict__ dst, int E, int* __restrict__ counts) {
    int e = blockIdx.x * blockDim.x + threadIdx.x;
    if (e < E) atomicAdd(&counts[dst[e]], 1);
}

__global__ void dinv_k(const int* __restrict__ counts, float* __restrict__ dinv, int N) {
    int i = blockIdx.x * blockDim.x + threadIdx.x;
    if (i < N) dinv[i] = rsqrtf((float)(counts[i] + 1));  // +1 self-loop
}

// zero dummy row N (64 fp16 each) of the three gather buffers
__global__ void zero_dummy(__half* __restrict__ b0, __half* __restrict__ b1,
                           __half* __restrict__ b2, int N) {
    int t = threadIdx.x;
    if (t >= 192) return;
    __half* b = (t < 64) ? b0 : (t < 128) ? b1 : b2;
    b[(size_t)N * 64 + (t & 63)] = __float2half(0.f);
}

// ---------------- 3-pass exclusive scan (1024 elems / block) ----------------

__global__ void scan_pass1(const int* __restrict__ counts, int N, int* __restrict__ bsum) {
    __shared__ int s[256];
    int t = threadIdx.x;
    int base = blockIdx.x * 1024 + t * 4;
    int sum = 0;
    for (int j = 0; j < 4; ++j) { int i = base + j; if (i < N) sum += counts[i]; }
    s[t] = sum; __syncthreads();
    for (int off = 128; off > 0; off >>= 1) {
        if (t < off) s[t] += s[t + off];
        __syncthreads();
    }
    if (t == 0) bsum[blockIdx.x] = s[0];
}

__global__ void scan_pass2(const int* __restrict__ bsum, int nb, int* __restrict__ boff) {
    if (blockIdx.x == 0 && threadIdx.x == 0) {
        int r = 0;
        for (int b = 0; b < nb; ++b) { boff[b] = r; r += bsum[b]; }
    }
}

__global__ void scan_pass3(const int* __restrict__ counts, int N,
                           const int* __restrict__ boff, int* __restrict__ rowptr, int E) {
    __shared__ int s[256];
    int t = threadIdx.x;
    int base = blockIdx.x * 1024 + t * 4;
    int c[4]; int sum = 0;
    for (int j = 0; j < 4; ++j) { int i = base + j; c[j] = (i < N) ? counts[i] : 0; sum += c[j]; }
    s[t] = sum; __syncthreads();
    for (int off = 1; off < 256; off <<= 1) {
        int v = (t >= off) ? s[t - off] : 0;
        __syncthreads();
        s[t] += v;
        __syncthreads();
    }
    int excl = s[t] - sum + boff[blockIdx.x];
    for (int j = 0; j < 4; ++j) {
        int i = base + j;
        if (i < N) { rowptr[i] = excl; excl += c[j]; }
    }
    if (blockIdx.x == 0 && t == 0) rowptr[N] = E;
}

// ---------------- CSR fill: col index only (4B scatter) ----------------

__global__ void fill_k(const int* __restrict__ src, const int* __restrict__ dst, int E,
                       const int* __restrict__ rowptr,
                       int* __restrict__ cursor, int* __restrict__ col) {
    int e = blockIdx.x * blockDim.x + threadIdx.x;
    if (e >= E) return;
    int s = src[e], d = dst[e];
    int pos = rowptr[d] + atomicAdd(&cursor[d], 1);
    col[pos] = s;
}

// ---------------- g0 = x @ W : LDS-tiled, 128 rows x 64 cols per block ----------------
// Emits fp32 g0 (teleport term) and the PRESCALED fp16 gather buffer
// g0h[n] = dinv[n] * g0[n]  (row N is a dummy, zeroed separately).

__global__ void __launch_bounds__(256) gemm_k(const float* __restrict__ x,
                                              const float* __restrict__ W,
                                              const float* __restrict__ dinv,
                                              float* __restrict__ g0,
                                              __half* __restrict__ g0h, int N) {
    __shared__ float Ws[128 * 64];    // 32 KB, row-major [k][j]
    __shared__ float xs[128 * 133];   // 68 KB, stride 133 -> conflict-free compute reads
    int t = threadIdx.x;
    for (int i = t; i < 128 * 64; i += 256) Ws[i] = W[i];
    int n0 = blockIdx.x * 128;
    for (int f = t; f < 128 * 32; f += 256) {  // f indexes a float4: r = f>>5, c4 = f&31
        int r = f >> 5, c4 = f & 31;
        int n = n0 + r;
        float4 v = (n < N) ? ((const float4*)x)[(size_t)n * 32 + c4]
                           : make_float4(0.f, 0.f, 0.f, 0.f);
        float* dp = &xs[r * 133 + c4 * 4];
        dp[0] = v.x; dp[1] = v.y; dp[2] = v.z; dp[3] = v.w;
    }
    __syncthreads();
    int tr = t & 15, tc = t >> 4;      // j0 = 4*tr (cols), r0 = 8*tc (rows)
    int j0 = tr * 4, r0 = tc * 8;
    float acc[8][4] = {};
#pragma unroll 4
    for (int k = 0; k < 128; ++k) {
        float4 wv = *(const float4*)&Ws[k * 64 + j0];
#pragma unroll
        for (int i = 0; i < 8; ++i) {
            float xv = xs[(r0 + i) * 133 + k];
            acc[i][0] += xv * wv.x; acc[i][1] += xv * wv.y;
            acc[i][2] += xv * wv.z; acc[i][3] += xv * wv.w;
        }
    }
#pragma unroll
    for (int i = 0; i < 8; ++i) {
        int n = n0 + r0 + i;
        if (n < N) {
            float4 v = make_float4(acc[i][0], acc[i][1], acc[i][2], acc[i][3]);
            *(float4*)&g0[(size_t)n * 64 + j0] = v;
            float dn = dinv[n];
            __half2 h01 = __floats2half2_rn(v.x * dn, v.y * dn);
            __half2 h23 = __floats2half2_rn(v.z * dn, v.w * dn);
            *(__half2*)&g0h[(size_t)n * 64 + j0]     = h01;
            *(__half2*)&g0h[(size_t)n * 64 + j0 + 2] = h23;
        }
    }
}

// ---------------- propagation ----------------
// Buffers hold g_hat = dinv[n]*h[n] (fp16, row = 128 B = full cache lines).
//   S = sum_e g_hat[src_e];  r = 0.9*dinv[d]*(S + g_hat[d]) + 0.1*g0[d]
// One wave per row; lanes 0-31 take even edges, 32-63 odd edges (one gather
// instruction covers two edges). 32 edges per batch = 16 gathers in flight
// (deep MLP; avg degree ~32 -> most rows are a single batch). Out-of-range
// edges are redirected to zeroed dummy row N (branch-free). Epilogue operand
// loads are hoisted above the loop to overlap the gather latency.

__global__ void __launch_bounds__(256) prop_k(const __half* __restrict__ gin,
                                              const float* __restrict__ g0,
                                              __half* __restrict__ gout,
                                              float* __restrict__ outf,
                                              const int* __restrict__ rowptr,
                                              const int* __restrict__ cols,
                                              const float* __restrict__ dinv,
                                              const float* __restrict__ bias,
                                              int N, int final_step) {
    int gw = (blockIdx.x * blockDim.x + threadIdx.x) >> 6;
    int lane = threadIdx.x & 63;
    if (gw >= N) return;
    int lh   = lane & 31;   // half2 index within the row (feature pair)
    int pair = lane >> 5;   // 0 = even edge, 1 = odd edge

    int beg = rowptr[gw], end = rowptr[gw + 1];
    int deg = end - beg;
    const __half2* gin2 = (const __half2*)gin;

    // hoisted epilogue operands (overlap with gather latency)
    float di   = dinv[gw];
    float2 gi  = __half22float2(gin2[(size_t)gw * 32 + lh]);   // self-loop term
    float2 g0v = ((const float2*)g0)[(size_t)gw * 32 + lh];

    float ax = 0.f, ay = 0.f;

    for (int base = 0; base < deg; base += 64) {
        int m = deg - base; if (m > 64) m = 64;
        int idx = beg + base + (lane < m ? lane : 0);
        int ci = __builtin_nontemporal_load(&cols[idx]);  // 64 edge cols / load
        for (int j = 0; j < m; j += 32) {                 // 32 edges, 16 gathers in flight
            float2 f[16];
#pragma unroll
            for (int u = 0; u < 16; ++u) {
                int e  = j + 2 * u;
                int ce = __builtin_amdgcn_readlane(ci, e);
                int co = __builtin_amdgcn_readlane(ci, e + 1);
                int c  = pair ? co : ce;
                if (e + pair >= m) c = N;                 // dummy zero row
                f[u] = __half22float2(gin2[(size_t)c * 32 + lh]);
            }
#pragma unroll
            for (int u = 0; u < 16; ++u) { ax += f[u].x; ay += f[u].y; }
        }
    }

    // merge the two edge-parity halves (lane ^ 32 holds the other parity)
    ax += __shfl(ax, lane ^ 32, 64);
    ay += __shfl(ay, lane ^ 32, 64);

    if (pair == 0) {
        float rx = 0.9f * di * (ax + gi.x) + 0.1f * g0v.x;
        float ry = 0.9f * di * (ay + gi.y) + 0.1f * g0v.y;
        if (final_step) {
            float2 bv = ((const float2*)bias)[lh];
            ((float2*)outf)[(size_t)gw * 32 + lh] = make_float2(rx + bv.x, ry + bv.y);
        } else {
            ((__half2*)gout)[(size_t)gw * 32 + lh] =
                __floats2half2_rn(di * rx, di * ry);
        }
    }
}

// ---------------- launch ----------------

extern "C" void kernel_launch(void* const* d_in, const int* in_sizes, int n_in,
                              void* d_out, int out_size, void* d_ws, size_t ws_size,
                              hipStream_t stream) {
    const float* x  = (const float*)d_in[0];
    const int*   ei = (const int*)d_in[1];
    const float* W  = (const float*)d_in[2];
    const float* b  = (const float*)d_in[3];
    float* out = (float*)d_out;

    const int N = in_sizes[0] / 128;
    const int E = in_sizes[1] / 2;
    const int* src = ei;
    const int* dst = ei + E;

    // workspace carve-up (256 B aligned)
    char* w = (char*)d_ws;
    size_t off = 0;
    auto alloc = [&](size_t bytes) -> void* {
        void* p = w + off;
        off += (bytes + 255) & ~(size_t)255;
        return p;
    };
    float*  g0     = (float*) alloc((size_t)N * 64 * 4);
    __half* g0h    = (__half*)alloc((size_t)(N + 1) * 64 * 2);  // +1 dummy row
    __half* bufA   = (__half*)alloc((size_t)(N + 1) * 64 * 2);
    __half* bufB   = (__half*)alloc((size_t)(N + 1) * 64 * 2);
    int*    cols   = (int*)   alloc((size_t)E * 4);
    int*    rowptr = (int*)   alloc((size_t)(N + 1) * 4);
    int*    counts = (int*)   alloc((size_t)N * 4);
    float*  dinvv  = (float*) alloc((size_t)N * 4);
    const int nb = (N + 1023) / 1024;
    int*    bsum   = (int*)   alloc((size_t)nb * 4);
    int*    boff   = (int*)   alloc((size_t)nb * 4);

    const int nblkN = (N + 255) / 256;
    const int nblkE = (E + 255) / 256;

    // build normalized adjacency (CSR by dst, col-only payload)
    zero_i32<<<nblkN, 256, 0, stream>>>(counts, N);
    hist_k<<<nblkE, 256, 0, stream>>>(dst, E, counts);
    dinv_k<<<nblkN, 256, 0, stream>>>(counts, dinvv, N);
    zero_dummy<<<1, 192, 0, stream>>>(g0h, bufA, bufB, N);
    scan_pass1<<<nb, 256, 0, stream>>>(counts, N, bsum);
    scan_pass2<<<1, 64, 0, stream>>>(bsum, nb, boff);
    scan_pass3<<<nb, 256, 0, stream>>>(counts, N, boff, rowptr, E);
    zero_i32<<<nblkN, 256, 0, stream>>>(counts, N);  // reuse as fill cursor
    fill_k<<<nblkE, 256, 0, stream>>>(src, dst, E, rowptr, counts, cols);

    // g0 = x @ W (propagation commutes with the linear head: (A h) W = A (h W))
    gemm_k<<<(N + 127) / 128, 256, 0, stream>>>(x, W, dinvv, g0, g0h, N);

    // K = 10 APPNP steps, fp16 ping-pong; last step writes fp32 d_out (+bias)
    const int nblkP = (N * 64 + 255) / 256;
    const __half* gin = g0h;
    __half* pp[2] = {bufA, bufB};
    for (int k = 0; k < 10; ++k) {
        const bool fin = (k == 9);
        __half* gout = pp[k & 1];
        prop_k<<<nblkP, 256, 0, stream>>>(gin, g0, gout, out, rowptr, cols,
                                          dinvv, b, N, fin ? 1 : 0);
        gin = gout;
    }
}

// Round 7
// 1072.712 us; speedup vs baseline: 1.8443x; 1.2139x over previous
//
#include <hip/hip_runtime.h>
#include <hip/hip_fp16.h>
#include <math.h>

// CSR is built on keys (dst<<3 | src>>14): each dst row's edges are grouped
// into 7 source-windows of 16384 nodes (2 MB of gather rows each). All waves
// sweep windows in the same order -> the active gather set stays ~L2-sized.

#define WSH 14          // window shift: 16384 rows/window
#define KSH 3           // 8 key slots per dst (7 used)

// ---------------- init / histogram / norm ----------------

__global__ void zero_i32(int* __restrict__ p, int n) {
    int i = blockIdx.x * blockDim.x + threadIdx.x;
    if (i < n) p[i] = 0;
}

__global__ void hist_k(const int* __restrict__ src, const int* __restrict__ dst,
                       int E, int* __restrict__ counts) {
    int e = blockIdx.x * blockDim.x + threadIdx.x;
    if (e < E) {
        int key = (dst[e] << KSH) | (src[e] >> WSH);
        atomicAdd(&counts[key], 1);
    }
}

// degree from rowptr (per-dst total = rowptr[(d+1)<<3] - rowptr[d<<3])
__global__ void dinv_k(const int* __restrict__ rowptr, float* __restrict__ dinv, int N) {
    int i = blockIdx.x * blockDim.x + threadIdx.x;
    if (i < N) {
        int deg = rowptr[(i + 1) << KSH] - rowptr[i << KSH];
        dinv[i] = rsqrtf((float)(deg + 1));  // +1 self-loop
    }
}

// zero dummy row N (64 fp16 each) of the three gather buffers
__global__ void zero_dummy(__half* __restrict__ b0, __half* __restrict__ b1,
                           __half* __restrict__ b2, int N) {
    int t = threadIdx.x;
    if (t >= 192) return;
    __half* b = (t < 64) ? b0 : (t < 128) ? b1 : b2;
    b[(size_t)N * 64 + (t & 63)] = __float2half(0.f);
}

// ---------------- 3-pass exclusive scan over nk elems (1024 / block) ----------------

__global__ void scan_pass1(const int* __restrict__ counts, int n, int* __restrict__ bsum) {
    __shared__ int s[256];
    int t = threadIdx.x;
    int base = blockIdx.x * 1024 + t * 4;
    int sum = 0;
    for (int j = 0; j < 4; ++j) { int i = base + j; if (i < n) sum += counts[i]; }
    s[t] = sum; __syncthreads();
    for (int off = 128; off > 0; off >>= 1) {
        if (t < off) s[t] += s[t + off];
        __syncthreads();
    }
    if (t == 0) bsum[blockIdx.x] = s[0];
}

// single-block parallel exclusive scan of nb block sums (nb <= 2048)
__global__ void scan_pass2(const int* __restrict__ bsum, int nb, int* __restrict__ boff) {
    __shared__ int s[256];
    int t = threadIdx.x;
    int C = (nb + 255) / 256;            // <= 8
    int b0 = t * C;
    int loc[8]; int sum = 0;
    for (int i = 0; i < C; ++i) {
        int v = (b0 + i < nb) ? bsum[b0 + i] : 0;
        loc[i] = sum; sum += v;
    }
    s[t] = sum; __syncthreads();
    for (int off = 1; off < 256; off <<= 1) {
        int v = (t >= off) ? s[t - off] : 0;
        __syncthreads();
        s[t] += v;
        __syncthreads();
    }
    int excl = s[t] - sum;
    for (int i = 0; i < C; ++i)
        if (b0 + i < nb) boff[b0 + i] = excl + loc[i];
}

__global__ void scan_pass3(const int* __restrict__ counts, int n,
                           const int* __restrict__ boff, int* __restrict__ rowptr, int E) {
    __shared__ int s[256];
    int t = threadIdx.x;
    int base = blockIdx.x * 1024 + t * 4;
    int c[4]; int sum = 0;
    for (int j = 0; j < 4; ++j) { int i = base + j; c[j] = (i < n) ? counts[i] : 0; sum += c[j]; }
    s[t] = sum; __syncthreads();
    for (int off = 1; off < 256; off <<= 1) {
        int v = (t >= off) ? s[t - off] : 0;
        __syncthreads();
        s[t] += v;
        __syncthreads();
    }
    int excl = s[t] - sum + boff[blockIdx.x];
    for (int j = 0; j < 4; ++j) {
        int i = base + j;
        if (i < n) { rowptr[i] = excl; excl += c[j]; }
    }
    if (blockIdx.x == 0 && t == 0) rowptr[n] = E;
}

// ---------------- CSR fill: col index only (4B scatter) ----------------

__global__ void fill_k(const int* __restrict__ src, const int* __restrict__ dst, int E,
                       const int* __restrict__ rowptr,
                       int* __restrict__ cursor, int* __restrict__ col) {
    int e = blockIdx.x * blockDim.x + threadIdx.x;
    if (e >= E) return;
    int s = src[e], d = dst[e];
    int key = (d << KSH) | (s >> WSH);
    int pos = rowptr[key] + atomicAdd(&cursor[key], 1);
    col[pos] = s;
}

// ---------------- g0 = x @ W : LDS-tiled, 128 rows x 64 cols per block ----------------
// Emits fp32 g0 (teleport term) and the PRESCALED fp16 gather buffer
// g0h[n] = dinv[n] * g0[n]  (row N is a dummy, zeroed separately).

__global__ void __launch_bounds__(256) gemm_k(const float* __restrict__ x,
                                              const float* __restrict__ W,
                                              const float* __restrict__ dinv,
                                              float* __restrict__ g0,
                                              __half* __restrict__ g0h, int N) {
    __shared__ float Ws[128 * 64];    // 32 KB, row-major [k][j]
    __shared__ float xs[128 * 133];   // 68 KB, stride 133 -> conflict-free compute reads
    int t = threadIdx.x;
    for (int i = t; i < 128 * 64; i += 256) Ws[i] = W[i];
    int n0 = blockIdx.x * 128;
    for (int f = t; f < 128 * 32; f += 256) {  // f indexes a float4: r = f>>5, c4 = f&31
        int r = f >> 5, c4 = f & 31;
        int n = n0 + r;
        float4 v = (n < N) ? ((const float4*)x)[(size_t)n * 32 + c4]
                           : make_float4(0.f, 0.f, 0.f, 0.f);
        float* dp = &xs[r * 133 + c4 * 4];
        dp[0] = v.x; dp[1] = v.y; dp[2] = v.z; dp[3] = v.w;
    }
    __syncthreads();
    int tr = t & 15, tc = t >> 4;      // j0 = 4*tr (cols), r0 = 8*tc (rows)
    int j0 = tr * 4, r0 = tc * 8;
    float acc[8][4] = {};
#pragma unroll 4
    for (int k = 0; k < 128; ++k) {
        float4 wv = *(const float4*)&Ws[k * 64 + j0];
#pragma unroll
        for (int i = 0; i < 8; ++i) {
            float xv = xs[(r0 + i) * 133 + k];
            acc[i][0] += xv * wv.x; acc[i][1] += xv * wv.y;
            acc[i][2] += xv * wv.z; acc[i][3] += xv * wv.w;
        }
    }
#pragma unroll
    for (int i = 0; i < 8; ++i) {
        int n = n0 + r0 + i;
        if (n < N) {
            float4 v = make_float4(acc[i][0], acc[i][1], acc[i][2], acc[i][3]);
            *(float4*)&g0[(size_t)n * 64 + j0] = v;
            float dn = dinv[n];
            __half2 h01 = __floats2half2_rn(v.x * dn, v.y * dn);
            __half2 h23 = __floats2half2_rn(v.z * dn, v.w * dn);
            *(__half2*)&g0h[(size_t)n * 64 + j0]     = h01;
            *(__half2*)&g0h[(size_t)n * 64 + j0 + 2] = h23;
        }
    }
}

// ---------------- propagation ----------------
// Buffers hold g_hat = dinv[n]*h[n] (fp16, row = 128 B = full cache lines).
//   S = sum_e g_hat[src_e];  r = 0.9*dinv[d]*(S + g_hat[d]) + 0.1*g0[d]
// One wave per dst row; lanes 0-31 take even edges, 32-63 odd edges (one
// gather covers two edges). Edges within a row are source-window sorted, so
// concurrent waves gather from the same ~2MB window -> per-XCD L2 hits.
// Inner loop: 8 edges (4 paired gathers) per iteration with early exit;
// final partial chunk is masked via the zeroed dummy row N (branch-free).

__global__ void __launch_bounds__(256) prop_k(const __half* __restrict__ gin,
                                              const float* __restrict__ g0,
                                              __half* __restrict__ gout,
                                              float* __restrict__ outf,
                                              const int* __restrict__ rowptr,
                                              const int* __restrict__ cols,
                                              const float* __restrict__ dinv,
                                              const float* __restrict__ bias,
                                              int N, int final_step) {
    int gw = (blockIdx.x * blockDim.x + threadIdx.x) >> 6;
    int lane = threadIdx.x & 63;
    if (gw >= N) return;
    int lh   = lane & 31;   // half2 index within the row (feature pair)
    int pair = lane >> 5;   // 0 = even edge, 1 = odd edge

    int beg = rowptr[gw << KSH];
    int end = rowptr[(gw + 1) << KSH];
    int deg = end - beg;
    const __half2* gin2 = (const __half2*)gin;

    // hoisted epilogue operands (overlap with gather latency)
    float di   = dinv[gw];
    float2 gi  = __half22float2(gin2[(size_t)gw * 32 + lh]);   // self-loop term
    float2 g0v = ((const float2*)g0)[(size_t)gw * 32 + lh];

    float ax = 0.f, ay = 0.f;

    for (int base = 0; base < deg; base += 64) {
        int m = deg - base; if (m > 64) m = 64;
        int idx = beg + base + (lane < m ? lane : 0);
        int ci = cols[idx];                       // 64 edge cols, one load
        int j = 0;
        for (; j + 7 < m; j += 8) {               // 8 edges, 4 paired gathers
            float2 f[4];
#pragma unroll
            for (int u = 0; u < 4; ++u) {
                int ce = __builtin_amdgcn_readlane(ci, j + 2 * u);
                int co = __builtin_amdgcn_readlane(ci, j + 2 * u + 1);
                int c  = pair ? co : ce;
                f[u] = __half22float2(gin2[(size_t)c * 32 + lh]);
            }
#pragma unroll
            for (int u = 0; u < 4; ++u) { ax += f[u].x; ay += f[u].y; }
        }
        if (j < m) {                              // masked final chunk (<8 edges)
            float2 f[4];
#pragma unroll
            for (int u = 0; u < 4; ++u) {
                int e  = j + 2 * u;
                int ce = __builtin_amdgcn_readlane(ci, e < 63 ? e : 63);
                int co = __builtin_amdgcn_readlane(ci, e + 1 < 63 ? e + 1 : 63);
                int c  = pair ? co : ce;
                if (e + pair >= m) c = N;         // dummy zero row
                f[u] = __half22float2(gin2[(size_t)c * 32 + lh]);
            }
#pragma unroll
            for (int u = 0; u < 4; ++u) { ax += f[u].x; ay += f[u].y; }
        }
    }

    // merge the two edge-parity halves (lane ^ 32 holds the other parity)
    ax += __shfl(ax, lane ^ 32, 64);
    ay += __shfl(ay, lane ^ 32, 64);

    if (pair == 0) {
        float rx = 0.9f * di * (ax + gi.x) + 0.1f * g0v.x;
        float ry = 0.9f * di * (ay + gi.y) + 0.1f * g0v.y;
        if (final_step) {
            float2 bv = ((const float2*)bias)[lh];
            ((float2*)outf)[(size_t)gw * 32 + lh] = make_float2(rx + bv.x, ry + bv.y);
        } else {
            ((__half2*)gout)[(size_t)gw * 32 + lh] =
                __floats2half2_rn(di * rx, di * ry);
        }
    }
}

// ---------------- launch ----------------

extern "C" void kernel_launch(void* const* d_in, const int* in_sizes, int n_in,
                              void* d_out, int out_size, void* d_ws, size_t ws_size,
                              hipStream_t stream) {
    const float* x  = (const float*)d_in[0];
    const int*   ei = (const int*)d_in[1];
    const float* W  = (const float*)d_in[2];
    const float* b  = (const float*)d_in[3];
    float* out = (float*)d_out;

    const int N = in_sizes[0] / 128;
    const int E = in_sizes[1] / 2;
    const int* src = ei;
    const int* dst = ei + E;
    const int nk = (N + 1) << KSH;       // key space (windowed rows)

    // workspace carve-up (256 B aligned)
    char* w = (char*)d_ws;
    size_t off = 0;
    auto alloc = [&](size_t bytes) -> void* {
        void* p = w + off;
        off += (bytes + 255) & ~(size_t)255;
        return p;
    };
    float*  g0     = (float*) alloc((size_t)N * 64 * 4);
    __half* g0h    = (__half*)alloc((size_t)(N + 1) * 64 * 2);  // +1 dummy row
    __half* bufA   = (__half*)alloc((size_t)(N + 1) * 64 * 2);
    __half* bufB   = (__half*)alloc((size_t)(N + 1) * 64 * 2);
    int*    cols   = (int*)   alloc((size_t)E * 4);
    int*    rowptr = (int*)   alloc((size_t)(nk + 1) * 4);
    int*    counts = (int*)   alloc((size_t)nk * 4);
    float*  dinvv  = (float*) alloc((size_t)N * 4);
    const int nb = (nk + 1023) / 1024;
    int*    bsum   = (int*)   alloc((size_t)nb * 4);
    int*    boff   = (int*)   alloc((size_t)nb * 4);

    const int nblkN = (N + 255) / 256;
    const int nblkK = (nk + 255) / 256;
    const int nblkE = (E + 255) / 256;

    // build window-sorted CSR (keys = dst<<3 | src>>14), col-only payload
    zero_i32<<<nblkK, 256, 0, stream>>>(counts, nk);
    hist_k<<<nblkE, 256, 0, stream>>>(src, dst, E, counts);
    zero_dummy<<<1, 192, 0, stream>>>(g0h, bufA, bufB, N);
    scan_pass1<<<nb, 256, 0, stream>>>(counts, nk, bsum);
    scan_pass2<<<1, 256, 0, stream>>>(bsum, nb, boff);
    scan_pass3<<<nb, 256, 0, stream>>>(counts, nk, boff, rowptr, E);
    dinv_k<<<nblkN, 256, 0, stream>>>(rowptr, dinvv, N);
    zero_i32<<<nblkK, 256, 0, stream>>>(counts, nk);  // reuse as fill cursor
    fill_k<<<nblkE, 256, 0, stream>>>(src, dst, E, rowptr, counts, cols);

    // g0 = x @ W (propagation commutes with the linear head: (A h) W = A (h W))
    gemm_k<<<(N + 127) / 128, 256, 0, stream>>>(x, W, dinvv, g0, g0h, N);

    // K = 10 APPNP steps, fp16 ping-pong; last step writes fp32 d_out (+bias)
    const int nblkP = (N * 64 + 255) / 256;
    const __half* gin = g0h;
    __half* pp[2] = {bufA, bufB};
    for (int k = 0; k < 10; ++k) {
        const bool fin = (k == 9);
        __half* gout = pp[k & 1];
        prop_k<<<nblkP, 256, 0, stream>>>(gin, g0, gout, out, rowptr, cols,
                                          dinvv, b, N, fin ? 1 : 0);
        gin = gout;
    }
}